// Round 2
// baseline (1989.768 us; speedup 1.0000x reference)
//
#include <hip/hip_runtime.h>

#define N_IN   262144
#define N_OUT  262144
#define KOFF   27
#define MPAIR  131072
#define C      64
#define EPS    1e-5f
#define NEG_SLOPE 0.01f

// ---- bucketed-merge parameters -------------------------------------------
#define BROWS   64                    // output rows per bucket (16 KB fp32 tile)
#define NBUCKET (N_OUT / BROWS)       // 4096
#define NKEY    (NBUCKET * KOFF)      // 110592 (bucket-major, k minor)
#define SLOTS   96                    // per-key capacity; lambda=32, P(ovfl)~1e-18

// ---------------------------------------------------------------------------
// Phase 1: bin every (k, pair) into its (out-bucket, k) key.
// record = im (18b) | (om & 63) << 18   -- fits one dword.
// ---------------------------------------------------------------------------
__global__ __launch_bounds__(256) void scatter_kernel(
    const int* __restrict__ in_map,
    const int* __restrict__ out_map,
    int*       __restrict__ cnt,
    unsigned int* __restrict__ recs)
{
    const int k = blockIdx.y;
    const int m = blockIdx.x * 256 + threadIdx.x;
    const size_t p = (size_t)k * MPAIR + m;
    const int om = out_map[p];
    const int im = in_map[p];
    const int key = (om >> 6) * KOFF + k;
    const int pos = atomicAdd(&cnt[key], 1);
    if (pos < SLOTS)
        recs[(size_t)key * SLOTS + pos] =
            (unsigned int)im | ((unsigned int)(om & 63) << 18);
}

// ---------------------------------------------------------------------------
// Phase 2: one block per bucket of 64 output rows. Waves stripe over k.
// Records bulk-loaded into 2 VGPRs per key (register-only access in loop).
// Groups of 4 records fetched with ONE global_load_dwordx4 per lane
// (lane l: row g*4+(l>>4), cols (l&15)*4). Depth-2 group pipeline.
// Contributions merge in an LDS tile (ds_add_f32); out written ONCE.
// ---------------------------------------------------------------------------
__global__ __launch_bounds__(256) void conv_merge_kernel(
    const float* __restrict__ feats,
    const float* __restrict__ W,
    const int*   __restrict__ cnt,
    const unsigned int* __restrict__ recs,
    float*       __restrict__ out,
    float*       __restrict__ stats)
{
    const int bucket = blockIdx.x;
    const int lane = threadIdx.x & 63;
    const int wave = threadIdx.x >> 6;

    __shared__ __align__(16) float tile[BROWS * C];     // 16 KB accumulator
    __shared__ __align__(16) float ring[4][2][4][C];    // 8 KB; reused for stats

    for (int i = threadIdx.x; i < BROWS * C; i += 256) tile[i] = 0.f;

    // Prefetch this wave's cnt values: lane j holds cnt of key (wave + 4*j).
    int myn = 0;
    if (lane < 7) {
        const int kk = wave + 4 * lane;
        if (kk < KOFF) myn = cnt[bucket * KOFF + kk];
    }
    __syncthreads();

    const int sub = lane >> 4;          // record-within-group 0..3
    const int c4  = (lane & 15) * 4;    // float4 column
    const int nkeys = (KOFF - wave + 3) >> 2;

    for (int j = 0; j < nkeys; ++j) {
        const int k = wave + 4 * j;
        int n = __builtin_amdgcn_readlane(myn, j);
        n = n > SLOTS ? SLOTS : n;
        if (n == 0) continue;
        const unsigned int* rbase = recs + (size_t)(bucket * KOFF + k) * SLOTS;

        // Bulk-load records into registers (padded allocation makes +64 safe).
        const unsigned int recv0 = rbase[lane];
        const unsigned int recv1 = rbase[64 + lane];

        // Register-resident weight column: wreg[i] = W[k][i][lane]
        float wreg[C];
        const float* Wk = W + (size_t)k * C * C;
        #pragma unroll
        for (int i = 0; i < C; ++i) wreg[i] = Wk[i * C + lane];

        // One dwordx4 per lane fetches 4 records' feats (rows sub, cols c4).
        auto LOADG = [&](int g) -> float4 {
            int rl = g * 4 + sub;
            rl = rl < n ? rl : n - 1;                   // clamp (dupes skipped later)
            unsigned int rec;
            if (g * 4 < 64) rec = __shfl((int)recv0, rl);
            else            rec = __shfl((int)recv1, rl - 64);
            const int im = (int)(rec & 0x3FFFFu);
            return *(const float4*)&feats[(size_t)im * C + c4];
        };

        // Compute one group from ring buffer B (literal): 2 interleaved acc chains.
        #define COMPUTE(gE, B) do {                                             \
            _Pragma("unroll")                                                   \
            for (int dp = 0; dp < 4; dp += 2) {                                 \
                const int ri0 = (gE) * 4 + dp, ri1 = ri0 + 1;                   \
                float acc0 = 0.f, acc1 = 0.f;                                   \
                _Pragma("unroll")                                               \
                for (int jj = 0; jj < 16; ++jj) {                               \
                    const float4 a = *(const float4*)&ring[wave][B][dp][4*jj];  \
                    const float4 b = *(const float4*)&ring[wave][B][dp+1][4*jj];\
                    acc0 = fmaf(a.x, wreg[4*jj+0], acc0);                       \
                    acc1 = fmaf(b.x, wreg[4*jj+0], acc1);                       \
                    acc0 = fmaf(a.y, wreg[4*jj+1], acc0);                       \
                    acc1 = fmaf(b.y, wreg[4*jj+1], acc1);                       \
                    acc0 = fmaf(a.z, wreg[4*jj+2], acc0);                       \
                    acc1 = fmaf(b.z, wreg[4*jj+2], acc1);                       \
                    acc0 = fmaf(a.w, wreg[4*jj+3], acc0);                       \
                    acc1 = fmaf(b.w, wreg[4*jj+3], acc1);                       \
                }                                                               \
                if (ri0 < n) {                                                  \
                    const unsigned int rr = (ri0 < 64)                          \
                        ? (unsigned int)__builtin_amdgcn_readlane((int)recv0, ri0)      \
                        : (unsigned int)__builtin_amdgcn_readlane((int)recv1, ri0 - 64);\
                    atomicAdd(&tile[(rr >> 18) * C + lane], acc0);              \
                }                                                               \
                if (ri1 < n) {                                                  \
                    const unsigned int rr = (ri1 < 64)                          \
                        ? (unsigned int)__builtin_amdgcn_readlane((int)recv0, ri1)      \
                        : (unsigned int)__builtin_amdgcn_readlane((int)recv1, ri1 - 64);\
                    atomicAdd(&tile[(rr >> 18) * C + lane], acc1);              \
                }                                                               \
            }                                                                   \
        } while (0)

        const int ngrp = (n + 3) >> 2;
        float4 fv0 = LOADG(0);
        float4 fv1;
        if (ngrp > 1) fv1 = LOADG(1);

        for (int g = 0; g < ngrp; g += 2) {
            // even group -> ring buf 0
            *(float4*)&ring[wave][0][sub][c4] = fv0;
            if (g + 2 < ngrp) fv0 = LOADG(g + 2);
            COMPUTE(g, 0);
            if (g + 1 < ngrp) {
                // odd group -> ring buf 1
                *(float4*)&ring[wave][1][sub][c4] = fv1;
                if (g + 3 < ngrp) fv1 = LOADG(g + 3);
                COMPUTE(g + 1, 1);
            }
        }
        #undef COMPUTE
    }
    __syncthreads();

    // Coalesced tile -> out store, with fused per-channel sum / sumsq.
    // Stats scratch overlays the ring (conv phase is done).
    float4* s_sum = (float4*)&ring[0][0][0][0];   // 4 KB
    float4* s_sq  = (float4*)&ring[2][0][0][0];   // 4 KB
    const int col4 = threadIdx.x & 15;
    const int rowg = threadIdx.x >> 4;
    float4 s = make_float4(0.f, 0.f, 0.f, 0.f);
    float4 q = make_float4(0.f, 0.f, 0.f, 0.f);
    #pragma unroll
    for (int jr = 0; jr < 4; ++jr) {
        const int row = rowg + jr * 16;
        float4 v = *(const float4*)&tile[row * C + col4 * 4];
        *(float4*)&out[(size_t)bucket * (BROWS * C) + row * C + col4 * 4] = v;
        s.x += v.x; s.y += v.y; s.z += v.z; s.w += v.w;
        q.x = fmaf(v.x, v.x, q.x); q.y = fmaf(v.y, v.y, q.y);
        q.z = fmaf(v.z, v.z, q.z); q.w = fmaf(v.w, v.w, q.w);
    }
    s_sum[threadIdx.x] = s; s_sq[threadIdx.x] = q;
    __syncthreads();

    if (threadIdx.x < 16) {
        float4 ts = make_float4(0.f, 0.f, 0.f, 0.f);
        float4 tq = make_float4(0.f, 0.f, 0.f, 0.f);
        for (int jr = 0; jr < 16; ++jr) {
            float4 a = s_sum[jr * 16 + threadIdx.x];
            float4 b = s_sq [jr * 16 + threadIdx.x];
            ts.x += a.x; ts.y += a.y; ts.z += a.z; ts.w += a.w;
            tq.x += b.x; tq.y += b.y; tq.z += b.z; tq.w += b.w;
        }
        const int c0 = threadIdx.x * 4;
        unsafeAtomicAdd(&stats[c0 + 0], ts.x);
        unsafeAtomicAdd(&stats[c0 + 1], ts.y);
        unsafeAtomicAdd(&stats[c0 + 2], ts.z);
        unsafeAtomicAdd(&stats[c0 + 3], ts.w);
        unsafeAtomicAdd(&stats[64 + c0 + 0], tq.x);
        unsafeAtomicAdd(&stats[64 + c0 + 1], tq.y);
        unsafeAtomicAdd(&stats[64 + c0 + 2], tq.z);
        unsafeAtomicAdd(&stats[64 + c0 + 3], tq.w);
    }
}

// ---------------------------------------------------------------------------
// LEGACY PATH (fallback if workspace too small): verified kernels.
// ---------------------------------------------------------------------------
__global__ __launch_bounds__(256) void conv_kernel(
    const float* __restrict__ feats,
    const float* __restrict__ W,
    const int*   __restrict__ in_map,
    const int*   __restrict__ out_map,
    float*       __restrict__ out)
{
    const int k    = blockIdx.y;
    const int lane = threadIdx.x & 63;
    const int wave = threadIdx.x >> 6;

    __shared__ float4 fr4[4][2][16];

    float wreg[C];
    const float* Wk = W + (size_t)k * C * C;
    #pragma unroll
    for (int i = 0; i < C; ++i) wreg[i] = Wk[i * C + lane];

    const int pair_base = (blockIdx.x * 4 + wave) * 64;
    const int my_pair   = pair_base + lane;
    const int my_im = in_map[(size_t)k * MPAIR + my_pair];
    const int my_om = out_map[(size_t)k * MPAIR + my_pair];

    int im0 = __builtin_amdgcn_readlane(my_im, 0);
    float fcur = feats[(size_t)im0 * C + lane];

    for (int p = 0; p < 64; ++p) {
        const int om  = __builtin_amdgcn_readlane(my_om, p);
        const int buf = p & 1;

        ((float*)&fr4[wave][buf][0])[lane] = fcur;

        if (p < 63) {
            int imn = __builtin_amdgcn_readlane(my_im, p + 1);
            fcur = feats[(size_t)imn * C + lane];
        }

        float acc = 0.f;
        #pragma unroll
        for (int j = 0; j < 16; ++j) {
            float4 f = fr4[wave][buf][j];
            acc = fmaf(f.x, wreg[4*j+0], acc);
            acc = fmaf(f.y, wreg[4*j+1], acc);
            acc = fmaf(f.z, wreg[4*j+2], acc);
            acc = fmaf(f.w, wreg[4*j+3], acc);
        }
        unsafeAtomicAdd(&out[(size_t)om * C + lane], acc);
    }
}

__global__ __launch_bounds__(256) void stats_kernel(
    const float* __restrict__ out, float* __restrict__ stats)
{
    __shared__ float4 s_sum[256], s_sq[256];
    const int col4 = threadIdx.x & 15;
    const int rowg = threadIdx.x >> 4;

    float4 s = make_float4(0.f, 0.f, 0.f, 0.f);
    float4 q = make_float4(0.f, 0.f, 0.f, 0.f);
    for (int row = blockIdx.x * 16 + rowg; row < N_OUT; row += gridDim.x * 16) {
        float4 v = *(const float4*)(out + (size_t)row * C + col4 * 4);
        s.x += v.x; s.y += v.y; s.z += v.z; s.w += v.w;
        q.x = fmaf(v.x, v.x, q.x); q.y = fmaf(v.y, v.y, q.y);
        q.z = fmaf(v.z, v.z, q.z); q.w = fmaf(v.w, v.w, q.w);
    }
    s_sum[threadIdx.x] = s; s_sq[threadIdx.x] = q;
    __syncthreads();

    if (threadIdx.x < 16) {
        float4 ts = make_float4(0.f, 0.f, 0.f, 0.f);
        float4 tq = make_float4(0.f, 0.f, 0.f, 0.f);
        for (int j = 0; j < 16; ++j) {
            float4 a = s_sum[j * 16 + threadIdx.x];
            float4 b = s_sq [j * 16 + threadIdx.x];
            ts.x += a.x; ts.y += a.y; ts.z += a.z; ts.w += a.w;
            tq.x += b.x; tq.y += b.y; tq.z += b.z; tq.w += b.w;
        }
        const int c0 = threadIdx.x * 4;
        unsafeAtomicAdd(&stats[c0 + 0], ts.x);
        unsafeAtomicAdd(&stats[c0 + 1], ts.y);
        unsafeAtomicAdd(&stats[c0 + 2], ts.z);
        unsafeAtomicAdd(&stats[c0 + 3], ts.w);
        unsafeAtomicAdd(&stats[64 + c0 + 0], tq.x);
        unsafeAtomicAdd(&stats[64 + c0 + 1], tq.y);
        unsafeAtomicAdd(&stats[64 + c0 + 2], tq.z);
        unsafeAtomicAdd(&stats[64 + c0 + 3], tq.w);
    }
}

// ---------------------------------------------------------------------------
// In-place BN (affine) + LeakyReLU (shared by both paths).
// ---------------------------------------------------------------------------
__global__ __launch_bounds__(256) void bn_kernel(
    float* __restrict__ out,
    const float* __restrict__ stats,
    const float* __restrict__ gamma,
    const float* __restrict__ beta)
{
    __shared__ __align__(16) float s_scale[C];
    __shared__ __align__(16) float s_shift[C];
    if (threadIdx.x < C) {
        const float inv_n = 1.0f / (float)N_OUT;
        float mean = stats[threadIdx.x] * inv_n;
        float var  = stats[C + threadIdx.x] * inv_n - mean * mean;
        float sc   = gamma[threadIdx.x] * rsqrtf(var + EPS);
        s_scale[threadIdx.x] = sc;
        s_shift[threadIdx.x] = beta[threadIdx.x] - mean * sc;
    }
    __syncthreads();

    const int col4 = threadIdx.x & 15;
    const int rowg = threadIdx.x >> 4;
    const float4 sc4 = *(const float4*)&s_scale[col4 * 4];
    const float4 sh4 = *(const float4*)&s_shift[col4 * 4];

    for (int row = blockIdx.x * 16 + rowg; row < N_OUT; row += gridDim.x * 16) {
        float4* p = (float4*)(out + (size_t)row * C + col4 * 4);
        float4 v = *p;
        v.x = fmaf(v.x, sc4.x, sh4.x);
        v.y = fmaf(v.y, sc4.y, sh4.y);
        v.z = fmaf(v.z, sc4.z, sh4.z);
        v.w = fmaf(v.w, sc4.w, sh4.w);
        v.x = v.x >= 0.f ? v.x : NEG_SLOPE * v.x;
        v.y = v.y >= 0.f ? v.y : NEG_SLOPE * v.y;
        v.z = v.z >= 0.f ? v.z : NEG_SLOPE * v.z;
        v.w = v.w >= 0.f ? v.w : NEG_SLOPE * v.w;
        *p = v;
    }
}

extern "C" void kernel_launch(void* const* d_in, const int* in_sizes, int n_in,
                              void* d_out, int out_size, void* d_ws, size_t ws_size,
                              hipStream_t stream) {
    const float* feats  = (const float*)d_in[0];
    const float* W      = (const float*)d_in[1];
    const float* gamma  = (const float*)d_in[2];
    const float* beta   = (const float*)d_in[3];
    const int*  in_map  = (const int*)d_in[4];
    const int*  out_map = (const int*)d_in[5];
    // d_in[6] = num_out (known constant N_OUT)

    float* out   = (float*)d_out;
    float* stats = (float*)d_ws;                       // 128 floats @ offset 0

    const size_t CNT_OFF = 1024;
    const size_t REC_OFF = CNT_OFF + (size_t)NKEY * 4;
    const size_t NEEDED  = REC_OFF + ((size_t)NKEY * SLOTS + 128) * 4;  // ~41 MB (+pad)

    if (ws_size >= NEEDED) {
        // --- bucketed-merge path: no global fp atomics, out written once ---
        int* cnt = (int*)((char*)d_ws + CNT_OFF);
        unsigned int* recs = (unsigned int*)((char*)d_ws + REC_OFF);

        hipMemsetAsync(stats, 0, 2 * C * sizeof(float), stream);
        hipMemsetAsync(cnt, 0, (size_t)NKEY * sizeof(int), stream);
        // NOTE: no memset of out -- conv_merge fully overwrites every row.

        dim3 sgrid(MPAIR / 256, KOFF);
        scatter_kernel<<<sgrid, 256, 0, stream>>>(in_map, out_map, cnt, recs);
        conv_merge_kernel<<<NBUCKET, 256, 0, stream>>>(feats, W, cnt, recs, out, stats);
        bn_kernel<<<512, 256, 0, stream>>>(out, stats, gamma, beta);
    } else {
        // --- legacy path (verified): atomic scatter + separate stats ---
        hipMemsetAsync(out, 0, (size_t)N_OUT * C * sizeof(float), stream);
        hipMemsetAsync(stats, 0, 2 * C * sizeof(float), stream);

        dim3 cgrid(MPAIR / 256, KOFF);
        conv_kernel<<<cgrid, 256, 0, stream>>>(feats, W, in_map, out_map, out);
        stats_kernel<<<256, 256, 0, stream>>>(out, stats);
        bn_kernel<<<512, 256, 0, stream>>>(out, stats, gamma, beta);
    }
}

// Round 3
// 1667.150 us; speedup vs baseline: 1.1935x; 1.1935x over previous
//
#include <hip/hip_runtime.h>

#define N_IN   262144
#define N_OUT  262144
#define KOFF   27
#define MPAIR  131072
#define C      64
#define EPS    1e-5f
#define NEG_SLOPE 0.01f

// ---- bucketed-merge parameters -------------------------------------------
#define BROWS   64                    // output rows per bucket (16 KB fp32 tile)
#define NBUCKET (N_OUT / BROWS)       // 4096
#define NKEY    (NBUCKET * KOFF)      // 110592 (bucket-major, k minor)
#define SLOTS   96                    // per-key capacity; lambda=32, P(ovfl)~1e-18

// ---------------------------------------------------------------------------
// Phase 0: transpose W[k][cin][cout] -> WT[k][cout][cin] so the per-key
// weight-column load is 16 coalesced dwordx4 per lane instead of 64 scalars.
// ---------------------------------------------------------------------------
__global__ __launch_bounds__(256) void wt_kernel(
    const float* __restrict__ W, float* __restrict__ WT)
{
    const int k  = blockIdx.x;
    __shared__ float t[64][65];
    const int c  = threadIdx.x & 63;
    const int r0 = threadIdx.x >> 6;
    #pragma unroll
    for (int rr = 0; rr < 16; ++rr) {
        const int i = rr * 4 + r0;
        t[i][c] = W[(size_t)k * C * C + i * C + c];
    }
    __syncthreads();
    #pragma unroll
    for (int rr = 0; rr < 16; ++rr) {
        const int cc = rr * 4 + r0;                  // output channel
        WT[((size_t)k * C + cc) * C + c] = t[c][cc]; // = W[k][c][cc]
    }
}

// ---------------------------------------------------------------------------
// Phase 1: bin every (k, pair) into its (out-bucket, k) key.
// record = im (18b) | (om & 63) << 18   -- fits one dword.
// ---------------------------------------------------------------------------
__global__ __launch_bounds__(256) void scatter_kernel(
    const int* __restrict__ in_map,
    const int* __restrict__ out_map,
    int*       __restrict__ cnt,
    unsigned int* __restrict__ recs)
{
    const int k = blockIdx.y;
    const int m = blockIdx.x * 256 + threadIdx.x;
    const size_t p = (size_t)k * MPAIR + m;
    const int om = out_map[p];
    const int im = in_map[p];
    const int key = (om >> 6) * KOFF + k;
    const int pos = atomicAdd(&cnt[key], 1);
    if (pos < SLOTS)
        recs[(size_t)key * SLOTS + pos] =
            (unsigned int)im | ((unsigned int)(om & 63) << 18);
}

// ---------------------------------------------------------------------------
// Phase 2: one block per bucket (64 output rows). Waves stripe over k.
// KEY IDEA: feats rows are wave-uniform (index via readlane -> SGPR), so the
// row loads scalarize to s_load_dwordx16 -> SGPRs (SMEM pipe). FMAs read the
// SGPR operand directly: NO LDS broadcast, NO VMEM in the record loop.
// 4 accumulator chains keep FMA issue-bound. Merge via ds_add_f32 (2-way,
// conflict-free). out written once, stats fused.
// ---------------------------------------------------------------------------
__global__ __launch_bounds__(256, 5) void conv_merge_kernel(
    const float* __restrict__ feats,
    const float* __restrict__ WT,
    const int*   __restrict__ cnt,
    const unsigned int* __restrict__ recs,
    float*       __restrict__ out,
    float*       __restrict__ stats)
{
    const int bucket = blockIdx.x;
    const int lane = threadIdx.x & 63;
    const int wave = threadIdx.x >> 6;

    __shared__ __align__(16) float tile[BROWS * C];   // 16 KB accumulator
    __shared__ __align__(16) float4 s_red[512];       // 8 KB stats scratch

    for (int i = threadIdx.x; i < BROWS * C / 4; i += 256)
        ((float4*)tile)[i] = make_float4(0.f, 0.f, 0.f, 0.f);

    // Prefetch this wave's cnt values: lane j holds cnt of key (wave + 4*j).
    int myn = 0;
    if (lane < 7) {
        const int kk = wave + 4 * lane;
        if (kk < KOFF) myn = cnt[bucket * KOFF + kk];
    }
    __syncthreads();

    const int nkeys = (KOFF - wave + 3) >> 2;

    for (int j = 0; j < nkeys; ++j) {
        const int k = wave + 4 * j;
        int n = __builtin_amdgcn_readlane(myn, j);
        n = n > SLOTS ? SLOTS : n;
        if (n == 0) continue;
        const unsigned int* rbase = recs + (size_t)(bucket * KOFF + k) * SLOTS;

        // Bulk-load records into registers (allocation padded, +64 safe).
        const int recv0 = (int)rbase[lane];
        const int recv1 = (int)rbase[64 + lane];

        // Register-resident weight column: wreg[i] = W[k][i][lane]
        float wreg[C];
        {
            const float4* wt = (const float4*)(WT + ((size_t)k * C + lane) * C);
            #pragma unroll
            for (int i4 = 0; i4 < 16; ++i4) {
                const float4 w = wt[i4];
                wreg[4*i4+0] = w.x; wreg[4*i4+1] = w.y;
                wreg[4*i4+2] = w.z; wreg[4*i4+3] = w.w;
            }
        }

        // One record: uniform row -> SGPRs, 64 FMAs (4 chains), 1 ds_add.
        #define RECORD_BODY(REC) do {                                          \
            const unsigned int rec_ = (unsigned int)(REC);                     \
            const int im_  = (int)(rec_ & 0x3FFFFu);                           \
            const int row_ = (int)(rec_ >> 18);                                \
            const float4* frow_ = (const float4*)(feats + (size_t)im_ * C);    \
            float a0 = 0.f, a1 = 0.f, a2 = 0.f, a3 = 0.f;                      \
            _Pragma("unroll")                                                  \
            for (int i4 = 0; i4 < 16; ++i4) {                                  \
                const float4 f = frow_[i4];       /* uniform -> s_load */      \
                a0 = fmaf(f.x, wreg[4*i4+0], a0);                              \
                a1 = fmaf(f.y, wreg[4*i4+1], a1);                              \
                a2 = fmaf(f.z, wreg[4*i4+2], a2);                              \
                a3 = fmaf(f.w, wreg[4*i4+3], a3);                              \
            }                                                                  \
            atomicAdd(&tile[row_ * C + lane], (a0 + a1) + (a2 + a3));          \
        } while (0)

        const int n0 = n < 64 ? n : 64;
        for (int r = 0; r < n0; ++r)
            RECORD_BODY(__builtin_amdgcn_readlane(recv0, r));
        for (int r = 64; r < n; ++r)
            RECORD_BODY(__builtin_amdgcn_readlane(recv1, r - 64));
        #undef RECORD_BODY
    }
    __syncthreads();

    // Coalesced tile -> out store, with fused per-channel sum / sumsq.
    float4* s_sum = &s_red[0];     // 256 float4
    float4* s_sq  = &s_red[256];   // 256 float4
    const int col4 = threadIdx.x & 15;
    const int rowg = threadIdx.x >> 4;
    float4 s = make_float4(0.f, 0.f, 0.f, 0.f);
    float4 q = make_float4(0.f, 0.f, 0.f, 0.f);
    #pragma unroll
    for (int jr = 0; jr < 4; ++jr) {
        const int row = rowg + jr * 16;
        float4 v = *(const float4*)&tile[row * C + col4 * 4];
        *(float4*)&out[(size_t)bucket * (BROWS * C) + row * C + col4 * 4] = v;
        s.x += v.x; s.y += v.y; s.z += v.z; s.w += v.w;
        q.x = fmaf(v.x, v.x, q.x); q.y = fmaf(v.y, v.y, q.y);
        q.z = fmaf(v.z, v.z, q.z); q.w = fmaf(v.w, v.w, q.w);
    }
    s_sum[threadIdx.x] = s; s_sq[threadIdx.x] = q;
    __syncthreads();

    if (threadIdx.x < 16) {
        float4 ts = make_float4(0.f, 0.f, 0.f, 0.f);
        float4 tq = make_float4(0.f, 0.f, 0.f, 0.f);
        for (int jr = 0; jr < 16; ++jr) {
            float4 a = s_sum[jr * 16 + threadIdx.x];
            float4 b = s_sq [jr * 16 + threadIdx.x];
            ts.x += a.x; ts.y += a.y; ts.z += a.z; ts.w += a.w;
            tq.x += b.x; tq.y += b.y; tq.z += b.z; tq.w += b.w;
        }
        const int c0 = threadIdx.x * 4;
        unsafeAtomicAdd(&stats[c0 + 0], ts.x);
        unsafeAtomicAdd(&stats[c0 + 1], ts.y);
        unsafeAtomicAdd(&stats[c0 + 2], ts.z);
        unsafeAtomicAdd(&stats[c0 + 3], ts.w);
        unsafeAtomicAdd(&stats[64 + c0 + 0], tq.x);
        unsafeAtomicAdd(&stats[64 + c0 + 1], tq.y);
        unsafeAtomicAdd(&stats[64 + c0 + 2], tq.z);
        unsafeAtomicAdd(&stats[64 + c0 + 3], tq.w);
    }
}

// ---------------------------------------------------------------------------
// LEGACY PATH (fallback if workspace too small): verified kernels.
// ---------------------------------------------------------------------------
__global__ __launch_bounds__(256) void conv_kernel(
    const float* __restrict__ feats,
    const float* __restrict__ W,
    const int*   __restrict__ in_map,
    const int*   __restrict__ out_map,
    float*       __restrict__ out)
{
    const int k    = blockIdx.y;
    const int lane = threadIdx.x & 63;
    const int wave = threadIdx.x >> 6;

    __shared__ float4 fr4[4][2][16];

    float wreg[C];
    const float* Wk = W + (size_t)k * C * C;
    #pragma unroll
    for (int i = 0; i < C; ++i) wreg[i] = Wk[i * C + lane];

    const int pair_base = (blockIdx.x * 4 + wave) * 64;
    const int my_pair   = pair_base + lane;
    const int my_im = in_map[(size_t)k * MPAIR + my_pair];
    const int my_om = out_map[(size_t)k * MPAIR + my_pair];

    int im0 = __builtin_amdgcn_readlane(my_im, 0);
    float fcur = feats[(size_t)im0 * C + lane];

    for (int p = 0; p < 64; ++p) {
        const int om  = __builtin_amdgcn_readlane(my_om, p);
        const int buf = p & 1;

        ((float*)&fr4[wave][buf][0])[lane] = fcur;

        if (p < 63) {
            int imn = __builtin_amdgcn_readlane(my_im, p + 1);
            fcur = feats[(size_t)imn * C + lane];
        }

        float acc = 0.f;
        #pragma unroll
        for (int j = 0; j < 16; ++j) {
            float4 f = fr4[wave][buf][j];
            acc = fmaf(f.x, wreg[4*j+0], acc);
            acc = fmaf(f.y, wreg[4*j+1], acc);
            acc = fmaf(f.z, wreg[4*j+2], acc);
            acc = fmaf(f.w, wreg[4*j+3], acc);
        }
        unsafeAtomicAdd(&out[(size_t)om * C + lane], acc);
    }
}

__global__ __launch_bounds__(256) void stats_kernel(
    const float* __restrict__ out, float* __restrict__ stats)
{
    __shared__ float4 s_sum[256], s_sq[256];
    const int col4 = threadIdx.x & 15;
    const int rowg = threadIdx.x >> 4;

    float4 s = make_float4(0.f, 0.f, 0.f, 0.f);
    float4 q = make_float4(0.f, 0.f, 0.f, 0.f);
    for (int row = blockIdx.x * 16 + rowg; row < N_OUT; row += gridDim.x * 16) {
        float4 v = *(const float4*)(out + (size_t)row * C + col4 * 4);
        s.x += v.x; s.y += v.y; s.z += v.z; s.w += v.w;
        q.x = fmaf(v.x, v.x, q.x); q.y = fmaf(v.y, v.y, q.y);
        q.z = fmaf(v.z, v.z, q.z); q.w = fmaf(v.w, v.w, q.w);
    }
    s_sum[threadIdx.x] = s; s_sq[threadIdx.x] = q;
    __syncthreads();

    if (threadIdx.x < 16) {
        float4 ts = make_float4(0.f, 0.f, 0.f, 0.f);
        float4 tq = make_float4(0.f, 0.f, 0.f, 0.f);
        for (int j = 0; j < 16; ++j) {
            float4 a = s_sum[j * 16 + threadIdx.x];
            float4 b = s_sq [j * 16 + threadIdx.x];
            ts.x += a.x; ts.y += a.y; ts.z += a.z; ts.w += a.w;
            tq.x += b.x; tq.y += b.y; tq.z += b.z; tq.w += b.w;
        }
        const int c0 = threadIdx.x * 4;
        unsafeAtomicAdd(&stats[c0 + 0], ts.x);
        unsafeAtomicAdd(&stats[c0 + 1], ts.y);
        unsafeAtomicAdd(&stats[c0 + 2], ts.z);
        unsafeAtomicAdd(&stats[c0 + 3], ts.w);
        unsafeAtomicAdd(&stats[64 + c0 + 0], tq.x);
        unsafeAtomicAdd(&stats[64 + c0 + 1], tq.y);
        unsafeAtomicAdd(&stats[64 + c0 + 2], tq.z);
        unsafeAtomicAdd(&stats[64 + c0 + 3], tq.w);
    }
}

// ---------------------------------------------------------------------------
// In-place BN (affine) + LeakyReLU (shared by both paths).
// ---------------------------------------------------------------------------
__global__ __launch_bounds__(256) void bn_kernel(
    float* __restrict__ out,
    const float* __restrict__ stats,
    const float* __restrict__ gamma,
    const float* __restrict__ beta)
{
    __shared__ __align__(16) float s_scale[C];
    __shared__ __align__(16) float s_shift[C];
    if (threadIdx.x < C) {
        const float inv_n = 1.0f / (float)N_OUT;
        float mean = stats[threadIdx.x] * inv_n;
        float var  = stats[C + threadIdx.x] * inv_n - mean * mean;
        float sc   = gamma[threadIdx.x] * rsqrtf(var + EPS);
        s_scale[threadIdx.x] = sc;
        s_shift[threadIdx.x] = beta[threadIdx.x] - mean * sc;
    }
    __syncthreads();

    const int col4 = threadIdx.x & 15;
    const int rowg = threadIdx.x >> 4;
    const float4 sc4 = *(const float4*)&s_scale[col4 * 4];
    const float4 sh4 = *(const float4*)&s_shift[col4 * 4];

    for (int row = blockIdx.x * 16 + rowg; row < N_OUT; row += gridDim.x * 16) {
        float4* p = (float4*)(out + (size_t)row * C + col4 * 4);
        float4 v = *p;
        v.x = fmaf(v.x, sc4.x, sh4.x);
        v.y = fmaf(v.y, sc4.y, sh4.y);
        v.z = fmaf(v.z, sc4.z, sh4.z);
        v.w = fmaf(v.w, sc4.w, sh4.w);
        v.x = v.x >= 0.f ? v.x : NEG_SLOPE * v.x;
        v.y = v.y >= 0.f ? v.y : NEG_SLOPE * v.y;
        v.z = v.z >= 0.f ? v.z : NEG_SLOPE * v.z;
        v.w = v.w >= 0.f ? v.w : NEG_SLOPE * v.w;
        *p = v;
    }
}

extern "C" void kernel_launch(void* const* d_in, const int* in_sizes, int n_in,
                              void* d_out, int out_size, void* d_ws, size_t ws_size,
                              hipStream_t stream) {
    const float* feats  = (const float*)d_in[0];
    const float* W      = (const float*)d_in[1];
    const float* gamma  = (const float*)d_in[2];
    const float* beta   = (const float*)d_in[3];
    const int*  in_map  = (const int*)d_in[4];
    const int*  out_map = (const int*)d_in[5];
    // d_in[6] = num_out (known constant N_OUT)

    float* out   = (float*)d_out;
    float* stats = (float*)d_ws;                       // 128 floats @ offset 0

    const size_t CNT_OFF = 1024;
    const size_t REC_OFF = CNT_OFF + (size_t)NKEY * 4;
    const size_t WT_OFF  = REC_OFF + ((size_t)NKEY * SLOTS + 128) * 4;
    const size_t NEEDED  = WT_OFF + (size_t)KOFF * C * C * 4;   // ~43 MB

    if (ws_size >= NEEDED) {
        // --- bucketed-merge path: SGPR-broadcast conv, no global fp atomics ---
        int* cnt = (int*)((char*)d_ws + CNT_OFF);
        unsigned int* recs = (unsigned int*)((char*)d_ws + REC_OFF);
        float* WT = (float*)((char*)d_ws + WT_OFF);

        hipMemsetAsync(stats, 0, 2 * C * sizeof(float), stream);
        hipMemsetAsync(cnt, 0, (size_t)NKEY * sizeof(int), stream);
        // NOTE: no memset of out -- conv_merge fully overwrites every row.

        wt_kernel<<<KOFF, 256, 0, stream>>>(W, WT);
        dim3 sgrid(MPAIR / 256, KOFF);
        scatter_kernel<<<sgrid, 256, 0, stream>>>(in_map, out_map, cnt, recs);
        conv_merge_kernel<<<NBUCKET, 256, 0, stream>>>(feats, WT, cnt, recs, out, stats);
        bn_kernel<<<512, 256, 0, stream>>>(out, stats, gamma, beta);
    } else {
        // --- legacy path (verified): atomic scatter + separate stats ---
        hipMemsetAsync(out, 0, (size_t)N_OUT * C * sizeof(float), stream);
        hipMemsetAsync(stats, 0, 2 * C * sizeof(float), stream);

        dim3 cgrid(MPAIR / 256, KOFF);
        conv_kernel<<<cgrid, 256, 0, stream>>>(feats, W, in_map, out_map, out);
        stats_kernel<<<256, 256, 0, stream>>>(out, stats);
        bn_kernel<<<512, 256, 0, stream>>>(out, stats, gamma, beta);
    }
}